// Round 1
// baseline (725.063 us; speedup 1.0000x reference)
//
#include <hip/hip_runtime.h>
#include <hip/hip_bf16.h>
#include <stdint.h>

// Problem: y[t][o] = sum_i x[t][i] * ((w_pos[o][i]>0) - (w_neg[o][i]>0))
// Collapse to ONE bf16 GEMM against ternary weights (exact in bf16).
// M=8192 (tokens), N=4096 (out), K=4096 (in). Output fp32.
// Workspace layout: [0,64MiB) x in bf16; [64MiB,96MiB) ternary weights bf16.

#define TOKENS 8192
#define DIN    4096
#define DOUT   4096
#define BM 128
#define BN 128
#define BK 32   // K elements staged per iteration

typedef __bf16  bf16x8  __attribute__((ext_vector_type(8)));
typedef float   floatx4 __attribute__((ext_vector_type(4)));

__device__ __forceinline__ void async_copy16(const void* g, void* l) {
  __builtin_amdgcn_global_load_lds(
      (const __attribute__((address_space(1))) void*)g,
      (__attribute__((address_space(3))) void*)l, 16, 0, 0);
}

__device__ __forceinline__ unsigned short f2bf_rne(float f) {
  union { float f; uint32_t u; } v; v.f = f;
  uint32_t u = v.u;
  u += 0x7fffu + ((u >> 16) & 1u);   // round-to-nearest-even
  return (unsigned short)(u >> 16);
}

__device__ __forceinline__ unsigned short tern_bits(float p, float n) {
  // bf16 bits of (p>0) - (n>0)  in {-1, 0, +1}
  bool bp = p > 0.0f, bn = n > 0.0f;
  return (unsigned short)(bp == bn ? 0u : (bp ? 0x3f80u : 0xbf80u));
}

__global__ void cvt_x_kernel(const float4* __restrict__ x,
                             ushort4* __restrict__ xb) {
  uint32_t i = blockIdx.x * blockDim.x + threadIdx.x;
  float4 v = x[i];
  ushort4 o;
  o.x = f2bf_rne(v.x); o.y = f2bf_rne(v.y);
  o.z = f2bf_rne(v.z); o.w = f2bf_rne(v.w);
  xb[i] = o;
}

__global__ void tern_kernel(const float4* __restrict__ wp,
                            const float4* __restrict__ wn,
                            ushort4* __restrict__ t) {
  uint32_t i = blockIdx.x * blockDim.x + threadIdx.x;
  float4 p = wp[i];
  float4 n = wn[i];
  ushort4 o;
  o.x = tern_bits(p.x, n.x);
  o.y = tern_bits(p.y, n.y);
  o.z = tern_bits(p.z, n.z);
  o.w = tern_bits(p.w, n.w);
  t[i] = o;
}

// C[M,N] = A[M,K] * B[N,K]^T, bf16 inputs, fp32 out. m97-style structure:
// 128x128 block tile, 4 waves in 2x2, each wave 64x64 = 4x4 of 16x16x32 MFMA.
__global__ __launch_bounds__(256) void gemm_bt(
    const unsigned short* __restrict__ A,   // [TOKENS][DIN] bf16
    const unsigned short* __restrict__ B,   // [DOUT][DIN]   bf16 ternary
    float* __restrict__ C)                  // [TOKENS][DOUT] fp32
{
  // Row-major tiles, NO padding: global_load_lds writes wave-uniform base +
  // lane*16, so LDS layout must be exactly the linear staging order.
  __shared__ __align__(16) unsigned short As[BM * BK];  // 8 KiB
  __shared__ __align__(16) unsigned short Bs[BN * BK];  // 8 KiB

  const int tid   = threadIdx.x;
  const int lane  = tid & 63;
  const int wave  = tid >> 6;      // 0..3
  const int waveM = wave >> 1;     // 0..1
  const int waveN = wave & 1;      // 0..1
  const int bm = blockIdx.y * BM;
  const int bn = blockIdx.x * BN;

  floatx4 acc[4][4];
#pragma unroll
  for (int i = 0; i < 4; ++i)
#pragma unroll
    for (int j = 0; j < 4; ++j)
      acc[i][j] = (floatx4)0.0f;

  // Staging: tile is 128 rows x 64 bytes = 8192 B. Thread t copies bytes
  // [t*16, t*16+16) (rows 0..63) and [4096+t*16, ...) (rows 64..127).
  const uint32_t o0 = (uint32_t)tid * 16u;
  const uint32_t r0 = o0 >> 6;     // tile row for chunk0 (0..63)
  const uint32_t c0 = o0 & 63u;    // byte within row
  const char* Ab = (const char*)A;
  const char* Bb = (const char*)B;
  char* AsB = (char*)As;
  char* BsB = (char*)Bs;
  uint32_t aoff0 = ((uint32_t)(bm + r0)      * DIN) * 2u + c0;
  uint32_t aoff1 = ((uint32_t)(bm + r0 + 64) * DIN) * 2u + c0;
  uint32_t boff0 = ((uint32_t)(bn + r0)      * DIN) * 2u + c0;
  uint32_t boff1 = ((uint32_t)(bn + r0 + 64) * DIN) * 2u + c0;

  // Fragment addressing (verified layouts):
  // A-operand: A[m = lane&15][k = (lane>>4)*8 + j]  -> one b128 per subtile
  // B-operand: B[k][n = lane&15] = W[n][k]          -> same addressing on Bs
  const int mrow = lane & 15;
  const int kq   = (lane >> 4) * 8;

  for (int k0 = 0; k0 < DIN; k0 += BK) {
    async_copy16(Ab + aoff0, AsB + o0);
    async_copy16(Ab + aoff1, AsB + o0 + 4096);
    async_copy16(Bb + boff0, BsB + o0);
    async_copy16(Bb + boff1, BsB + o0 + 4096);
    aoff0 += BK * 2; aoff1 += BK * 2; boff0 += BK * 2; boff1 += BK * 2;
    __syncthreads();   // drains vmcnt: staged tile visible

    bf16x8 a[4], b[4];
#pragma unroll
    for (int i = 0; i < 4; ++i) {
      a[i] = *(const bf16x8*)(As + (waveM * 64 + i * 16 + mrow) * BK + kq);
      b[i] = *(const bf16x8*)(Bs + (waveN * 64 + i * 16 + mrow) * BK + kq);
    }
#pragma unroll
    for (int i = 0; i < 4; ++i)
#pragma unroll
      for (int j = 0; j < 4; ++j)
        acc[i][j] = __builtin_amdgcn_mfma_f32_16x16x32_bf16(a[i], b[j],
                                                            acc[i][j], 0, 0, 0);
    __syncthreads();   // all ds_reads done before next overwrite
  }

  // Epilogue. C/D layout (HW-verified): col = lane&15, row = (lane>>4)*4 + reg
  const int col0 = bn + waveN * 64 + (lane & 15);
  const int row0 = bm + waveM * 64 + (lane >> 4) * 4;
  float* Cp = C + (size_t)row0 * DOUT + col0;
#pragma unroll
  for (int i = 0; i < 4; ++i)
#pragma unroll
    for (int j = 0; j < 4; ++j)
#pragma unroll
      for (int r = 0; r < 4; ++r)
        Cp[(size_t)(i * 16 + r) * DOUT + j * 16] = acc[i][j][r];
}

extern "C" void kernel_launch(void* const* d_in, const int* in_sizes, int n_in,
                              void* d_out, int out_size, void* d_ws, size_t ws_size,
                              hipStream_t stream) {
  const float* x  = (const float*)d_in[0];   // [8192, 4096]
  const float* wp = (const float*)d_in[1];   // [4096, 4096]
  const float* wn = (const float*)d_in[2];   // [4096, 4096]
  float* out = (float*)d_out;                // [8192, 4096] fp32

  // Workspace: needs 96 MiB (64 MiB x_bf16 + 32 MiB tern_bf16).
  unsigned short* xb   = (unsigned short*)d_ws;
  unsigned short* tern = xb + (size_t)TOKENS * DIN;

  cvt_x_kernel<<<(TOKENS * DIN / 4) / 256, 256, 0, stream>>>(
      (const float4*)x, (ushort4*)xb);
  tern_kernel<<<(DOUT * DIN / 4) / 256, 256, 0, stream>>>(
      (const float4*)wp, (const float4*)wn, (ushort4*)tern);

  dim3 grid(DOUT / BN, TOKENS / BM);   // (32, 64)
  gemm_bt<<<grid, 256, 0, stream>>>(xb, tern, out);
}

// Round 2
// 717.296 us; speedup vs baseline: 1.0108x; 1.0108x over previous
//
#include <hip/hip_runtime.h>
#include <hip/hip_bf16.h>
#include <stdint.h>

// y[t][o] = sum_i x[t][i] * ((w_pos[o][i]>0) - (w_neg[o][i]>0))
// One bf16 GEMM vs ternary weights (ternary is exact in bf16).
// M=8192, N=4096, K=4096. fp32 out.
// ws: [0,64MiB) x_bf16 ; [64MiB,96MiB) tern_bf16.

#define TOKENS 8192
#define DIN    4096
#define DOUT   4096
#define BM 128
#define BN 128
#define BK 32

typedef __bf16  bf16x8  __attribute__((ext_vector_type(8)));
typedef float   floatx4 __attribute__((ext_vector_type(4)));

__device__ __forceinline__ void async_copy16(const void* g, void* l) {
  __builtin_amdgcn_global_load_lds(
      (const __attribute__((address_space(1))) void*)g,
      (__attribute__((address_space(3))) void*)l, 16, 0, 0);
}

__device__ __forceinline__ unsigned short f2bf_rne(float f) {
  union { float f; uint32_t u; } v; v.f = f;
  uint32_t u = v.u;
  u += 0x7fffu + ((u >> 16) & 1u);
  return (unsigned short)(u >> 16);
}

__device__ __forceinline__ unsigned short tern_bits(float p, float n) {
  bool bp = p > 0.0f, bn = n > 0.0f;
  return (unsigned short)(bp == bn ? 0u : (bp ? 0x3f80u : 0xbf80u));
}

// Grid-stride x4: 8192 blocks x 256 thr, 4 float4 per thread.
__global__ __launch_bounds__(256) void cvt_x_kernel(
    const float4* __restrict__ x, ushort4* __restrict__ xb) {
  const uint32_t stride = gridDim.x * blockDim.x;
  uint32_t i = blockIdx.x * blockDim.x + threadIdx.x;
#pragma unroll
  for (int it = 0; it < 4; ++it, i += stride) {
    float4 v = x[i];
    ushort4 o;
    o.x = f2bf_rne(v.x); o.y = f2bf_rne(v.y);
    o.z = f2bf_rne(v.z); o.w = f2bf_rne(v.w);
    xb[i] = o;
  }
}

// 4096 blocks x 256 thr, 4 float4-pairs per thread.
__global__ __launch_bounds__(256) void tern_kernel(
    const float4* __restrict__ wp, const float4* __restrict__ wn,
    ushort4* __restrict__ t) {
  const uint32_t stride = gridDim.x * blockDim.x;
  uint32_t i = blockIdx.x * blockDim.x + threadIdx.x;
#pragma unroll
  for (int it = 0; it < 4; ++it, i += stride) {
    float4 p = wp[i];
    float4 n = wn[i];
    ushort4 o;
    o.x = tern_bits(p.x, n.x);
    o.y = tern_bits(p.y, n.y);
    o.z = tern_bits(p.z, n.z);
    o.w = tern_bits(p.w, n.w);
    t[i] = o;
  }
}

// C[M,N] = A[M,K] * B[N,K]^T. 128x128 tile, 4 waves 2x2, each 64x64 via
// 4x4 of mfma_f32_16x16x32_bf16.
//
// LDS swizzle: row r of a tile is 64 B = 4 chunks of 16 B. Chunk c is stored
// at slot (c ^ ((r>>1)&3)). Staging applies the inverse on the GLOBAL address
// (per-thread constant — global_load_lds keeps its linear lane->LDS mapping);
// fragment reads apply it on the LDS address (per-lane constant). Result:
// the 16 lanes of each b128 fragment read cover all 8 bank groups 2-way,
// and 2-way is conflict-free.
__global__ __launch_bounds__(256) void gemm_bt(
    const unsigned short* __restrict__ A,   // [TOKENS][DIN] bf16
    const unsigned short* __restrict__ B,   // [DOUT][DIN]   bf16 ternary
    float* __restrict__ C)                  // [TOKENS][DOUT] fp32
{
  __shared__ __align__(16) unsigned short As[BM * BK];  // 8 KiB
  __shared__ __align__(16) unsigned short Bs[BN * BK];  // 8 KiB

  const int tid   = threadIdx.x;
  const int lane  = tid & 63;
  const int waveM = (tid >> 6) >> 1;   // 0..1
  const int waveN = (tid >> 6) & 1;    // 0..1
  const int bm = blockIdx.y * BM;
  const int bn = blockIdx.x * BN;

  floatx4 acc[4][4];
#pragma unroll
  for (int i = 0; i < 4; ++i)
#pragma unroll
    for (int j = 0; j < 4; ++j)
      acc[i][j] = (floatx4)0.0f;

  // Staging: thread t fills LDS bytes [t*16, t*16+16) (rows 0..63) and
  // [4096 + t*16, ...) (rows 64..127) of each tile. LDS slot s of row r
  // holds global chunk c = s ^ ((r>>1)&3); note (r+64) keeps the same xor.
  const uint32_t o0 = (uint32_t)tid * 16u;
  const uint32_t r0 = o0 >> 6;             // 0..63
  const uint32_t s0 = (o0 >> 4) & 3u;
  const uint32_t c0 = (s0 ^ ((r0 >> 1) & 3u)) * 16u;  // global byte-chunk
  const char* Ab = (const char*)A;
  const char* Bb = (const char*)B;
  char* AsB = (char*)As;
  char* BsB = (char*)Bs;
  uint32_t aoff0 = ((uint32_t)(bm + r0)      * DIN) * 2u + c0;
  uint32_t aoff1 = ((uint32_t)(bm + r0 + 64) * DIN) * 2u + c0;
  uint32_t boff0 = ((uint32_t)(bn + r0)      * DIN) * 2u + c0;
  uint32_t boff1 = ((uint32_t)(bn + r0 + 64) * DIN) * 2u + c0;

  // Fragment read: lane wants (row = tileRow, k-chunk q = lane>>4).
  // Swizzled byte slot within the 64B row: (q ^ ((mrow>>1)&3))*16 —
  // row bases are multiples of 16 so (row>>1)&3 == (mrow>>1)&3.
  const int mrow = lane & 15;
  const int q    = lane >> 4;
  const int xs   = (q ^ ((mrow >> 1) & 3)) * 16;

  for (int k0 = 0; k0 < DIN; k0 += BK) {
    async_copy16(Ab + aoff0, AsB + o0);
    async_copy16(Ab + aoff1, AsB + o0 + 4096);
    async_copy16(Bb + boff0, BsB + o0);
    async_copy16(Bb + boff1, BsB + o0 + 4096);
    aoff0 += BK * 2; aoff1 += BK * 2; boff0 += BK * 2; boff1 += BK * 2;
    __syncthreads();

    bf16x8 a[4], b[4];
#pragma unroll
    for (int i = 0; i < 4; ++i) {
      a[i] = *(const bf16x8*)(AsB + (waveM * 64 + i * 16 + mrow) * 64 + xs);
      b[i] = *(const bf16x8*)(BsB + (waveN * 64 + i * 16 + mrow) * 64 + xs);
    }
#pragma unroll
    for (int i = 0; i < 4; ++i)
#pragma unroll
      for (int j = 0; j < 4; ++j)
        acc[i][j] = __builtin_amdgcn_mfma_f32_16x16x32_bf16(a[i], b[j],
                                                            acc[i][j], 0, 0, 0);
    __syncthreads();
  }

  // C/D layout: col = lane&15, row = (lane>>4)*4 + reg.
  const int col0 = bn + waveN * 64 + (lane & 15);
  const int row0 = bm + waveM * 64 + (lane >> 4) * 4;
  float* Cp = C + (size_t)row0 * DOUT + col0;
#pragma unroll
  for (int i = 0; i < 4; ++i)
#pragma unroll
    for (int j = 0; j < 4; ++j)
#pragma unroll
      for (int r = 0; r < 4; ++r)
        Cp[(size_t)(i * 16 + r) * DOUT + j * 16] = acc[i][j][r];
}

extern "C" void kernel_launch(void* const* d_in, const int* in_sizes, int n_in,
                              void* d_out, int out_size, void* d_ws, size_t ws_size,
                              hipStream_t stream) {
  const float* x  = (const float*)d_in[0];   // [8192, 4096] fp32
  const float* wp = (const float*)d_in[1];   // [4096, 4096] fp32
  const float* wn = (const float*)d_in[2];   // [4096, 4096] fp32
  float* out = (float*)d_out;                // [8192, 4096] fp32

  unsigned short* xb   = (unsigned short*)d_ws;
  unsigned short* tern = xb + (size_t)TOKENS * DIN;

  // TOKENS*DIN/4 float4s, 4 per thread -> 8192 blocks
  cvt_x_kernel<<<TOKENS * DIN / 4 / 4 / 256, 256, 0, stream>>>(
      (const float4*)x, (ushort4*)xb);
  // DOUT*DIN/4 float4s, 4 per thread -> 4096 blocks
  tern_kernel<<<DOUT * DIN / 4 / 4 / 256, 256, 0, stream>>>(
      (const float4*)wp, (const float4*)wn, (ushort4*)tern);

  dim3 grid(DOUT / BN, TOKENS / BM);   // (32, 64)
  gemm_bt<<<grid, 256, 0, stream>>>(xb, tern, out);
}